// Round 1
// baseline (587.606 us; speedup 1.0000x reference)
//
#include <hip/hip_runtime.h>

#define NN 100000
#define NE 1600000
#define F  32
#define TOT (2*NN)                 // concatenated out|in degree arrays
#define SCAN_B 1024
#define SCAN_G ((TOT + SCAN_B - 1) / SCAN_B)   // 196

// ---- init: zero counters + gsum ----
__global__ void init_kernel(int* __restrict__ cnt, float* __restrict__ gsum) {
    int i = blockIdx.x * blockDim.x + threadIdx.x;
    if (i < TOT) cnt[i] = 0;
    if (i == 0) gsum[0] = 0.f;
}

// ---- count degrees (out by src, in by dst) into one concatenated array ----
__global__ void count_kernel(const int* __restrict__ src, const int* __restrict__ dst,
                             int* __restrict__ cnt) {
    int e = blockIdx.x * blockDim.x + threadIdx.x;
    if (e >= NE) return;
    atomicAdd(&cnt[src[e]], 1);
    atomicAdd(&cnt[NN + dst[e]], 1);
}

// ---- hierarchical exclusive scan over cnt[TOT] -> X[TOT] (+ sentinel later) ----
__global__ __launch_bounds__(1024) void scan1_kernel(const int* __restrict__ cnt,
                                                     int* __restrict__ X,
                                                     int* __restrict__ bsum) {
    __shared__ int s[SCAN_B];
    int t = threadIdx.x;
    int g = blockIdx.x * SCAN_B + t;
    int v = (g < TOT) ? cnt[g] : 0;
    s[t] = v;
    __syncthreads();
    for (int off = 1; off < SCAN_B; off <<= 1) {
        int a = (t >= off) ? s[t - off] : 0;
        __syncthreads();
        s[t] += a;
        __syncthreads();
    }
    if (g < TOT) X[g] = s[t] - v;          // block-local exclusive
    if (t == SCAN_B - 1) bsum[blockIdx.x] = s[t];
}

__global__ __launch_bounds__(256) void scan2_kernel(int* __restrict__ bsum) {
    __shared__ int s[256];
    int t = threadIdx.x;
    int v = (t < SCAN_G) ? bsum[t] : 0;
    s[t] = v;
    __syncthreads();
    for (int off = 1; off < 256; off <<= 1) {
        int a = (t >= off) ? s[t - off] : 0;
        __syncthreads();
        s[t] += a;
        __syncthreads();
    }
    if (t < SCAN_G) bsum[t] = s[t] - v;    // exclusive block offsets
}

// finalize offsets, write sentinel, and init scatter cursors (cur = cnt reused)
__global__ __launch_bounds__(1024) void scan3_kernel(int* __restrict__ X,
                                                     const int* __restrict__ bsum,
                                                     int* __restrict__ cur) {
    int g = blockIdx.x * SCAN_B + threadIdx.x;
    if (g < TOT) {
        int v = X[g] + bsum[blockIdx.x];
        X[g] = v;
        cur[g] = v;
    }
    if (g == 0) X[TOT] = 2 * NE;           // sentinel: end of in-part for node NN-1
}

// ---- fill CSR adjacency: adj[j] = {neighbor, weight_bits}; out in [0,E), in in [E,2E) ----
__global__ void scatter_kernel(const int* __restrict__ src, const int* __restrict__ dst,
                               const float* __restrict__ ew,
                               int* __restrict__ cur, int2* __restrict__ adj) {
    int e = blockIdx.x * blockDim.x + threadIdx.x;
    if (e >= NE) return;
    int s = src[e], d = dst[e];
    int wb = __float_as_int(ew[e]);
    int p = atomicAdd(&cur[s], 1);
    adj[p] = make_int2(d, wb);
    int q = atomicAdd(&cur[NN + d], 1);
    adj[q] = make_int2(s, wb);
}

// ---- fused gather + gates + reduction. 4 lanes per node, 8 features per lane. ----
// H = 0 initially => only the first 32 rows (c<32) of each 64x32 W slice matter,
// R-gate is dead, H_new = (1-sigmoid(gz)) * tanh(gh).
__global__ __launch_bounds__(256) void RecurrentGCN_69587060130083_kernel(
    const float* __restrict__ x,
    const int* __restrict__ X,          // CSR offsets [2*NN+1]
    const int2* __restrict__ adj,       // [2*NE]
    const float* __restrict__ Wz, const float* __restrict__ bz,
    const float* __restrict__ Wh, const float* __restrict__ bh,
    const float* __restrict__ Wl,
    float* __restrict__ gsum)
{
    // transposed [f][c] so per-f dot reads contiguous 8-float slices
    __shared__ float sWz0[1024], sWzo[1024], sWzi[1024];
    __shared__ float sWh0[1024], sWho[1024], sWhi[1024];
    __shared__ float sbz[32], sbh[32], swl[32];
    __shared__ float wsum[4];
    int tid = threadIdx.x;

    for (int idx = tid; idx < 1024; idx += 256) {
        int c = idx >> 5, f = idx & 31;
        int tr = f * 32 + c;
        // W[dir,k,c,f] flat = dir*4096 + k*2048 + c*32 + f ; only c<32 matters (H=0)
        sWz0[tr] = Wz[idx] + Wz[4096 + idx];
        sWzo[tr] = Wz[2048 + idx];
        sWzi[tr] = Wz[6144 + idx];
        sWh0[tr] = Wh[idx] + Wh[4096 + idx];
        sWho[tr] = Wh[2048 + idx];
        sWhi[tr] = Wh[6144 + idx];
    }
    if (tid < 32) {
        sbz[tid] = bz[tid];
        sbh[tid] = bh[tid];
        swl[tid] = Wl[tid];
    }
    __syncthreads();

    int q = tid & 3;                       // quartet lane: features [q*8, q*8+8)
    int i = (blockIdx.x * 256 + tid) >> 2; // node index (64 nodes per block)
    float s_acc = 0.f;

    if (i < NN) {
        const int cbase = q * 8;
        float xv[8], tov[8], tiv[8];
#pragma unroll
        for (int c = 0; c < 8; c++) { tov[c] = 0.f; tiv[c] = 0.f; }

        const float4* xr = (const float4*)(x + ((size_t)i << 5) + cbase);
        float4 p0 = xr[0], p1 = xr[1];
        xv[0] = p0.x; xv[1] = p0.y; xv[2] = p0.z; xv[3] = p0.w;
        xv[4] = p1.x; xv[5] = p1.y; xv[6] = p1.z; xv[7] = p1.w;

        // out-direction gather: contiguous CSR range, loads pipeline freely
        int r0 = X[i], r1 = X[i + 1];
        float deg_o = 0.f;
        for (int j = r0; j < r1; ++j) {
            int2 a = adj[j];
            float w = __int_as_float(a.y);
            deg_o += w;
            const float4* nr = (const float4*)(x + ((size_t)a.x << 5) + cbase);
            float4 b0 = nr[0], b1 = nr[1];
            tov[0] += w * b0.x; tov[1] += w * b0.y; tov[2] += w * b0.z; tov[3] += w * b0.w;
            tov[4] += w * b1.x; tov[5] += w * b1.y; tov[6] += w * b1.z; tov[7] += w * b1.w;
        }
        // in-direction gather
        int r2 = X[NN + i], r3 = X[NN + i + 1];
        float deg_i = 0.f;
        for (int j = r2; j < r3; ++j) {
            int2 a = adj[j];
            float w = __int_as_float(a.y);
            deg_i += w;
            const float4* nr = (const float4*)(x + ((size_t)a.x << 5) + cbase);
            float4 b0 = nr[0], b1 = nr[1];
            tiv[0] += w * b0.x; tiv[1] += w * b0.y; tiv[2] += w * b0.z; tiv[3] += w * b0.w;
            tiv[4] += w * b1.x; tiv[5] += w * b1.y; tiv[6] += w * b1.z; tiv[7] += w * b1.w;
        }
        float dio = 1.f / deg_o, dii = 1.f / deg_i;
#pragma unroll
        for (int c = 0; c < 8; c++) { tov[c] *= dio; tiv[c] *= dii; }

        // gates: per-f partial dot over this lane's 8 channels, quartet shuffle-reduce
#pragma unroll 4
        for (int f = 0; f < 32; ++f) {
            const float* wz0 = &sWz0[f * 32 + cbase];
            const float* wzo = &sWzo[f * 32 + cbase];
            const float* wzi = &sWzi[f * 32 + cbase];
            const float* wh0 = &sWh0[f * 32 + cbase];
            const float* who = &sWho[f * 32 + cbase];
            const float* whi = &sWhi[f * 32 + cbase];
            float pz = 0.f, ph = 0.f;
#pragma unroll
            for (int c = 0; c < 8; c++) {
                pz += xv[c] * wz0[c] + tov[c] * wzo[c] + tiv[c] * wzi[c];
                ph += xv[c] * wh0[c] + tov[c] * who[c] + tiv[c] * whi[c];
            }
            pz += __shfl_xor(pz, 1); pz += __shfl_xor(pz, 2);
            ph += __shfl_xor(ph, 1); ph += __shfl_xor(ph, 2);
            if (q == (f & 3)) {
                float gz = pz + sbz[f];
                float gh = ph + sbh[f];
                float Z  = 1.f / (1.f + __expf(-gz));
                float Ht = tanhf(gh);
                float hv = (1.f - Z) * Ht;
                hv = hv > 0.f ? hv : 0.f;
                s_acc += hv * swl[f];
            }
        }
    }

    // wave64 reduce -> cross-wave via LDS -> one atomic per block
#pragma unroll
    for (int off = 32; off > 0; off >>= 1) s_acc += __shfl_down(s_acc, off);
    if ((tid & 63) == 0) wsum[tid >> 6] = s_acc;
    __syncthreads();
    if (tid == 0) atomicAdd(gsum, wsum[0] + wsum[1] + wsum[2] + wsum[3]);
}

__global__ void finalize_kernel(const float* __restrict__ gsum,
                                const float* __restrict__ blin,
                                float* __restrict__ out) {
    out[0] = gsum[0] / (float)NN + blin[0];
}

extern "C" void kernel_launch(void* const* d_in, const int* in_sizes, int n_in,
                              void* d_out, int out_size, void* d_ws, size_t ws_size,
                              hipStream_t stream) {
    const float* x  = (const float*)d_in[0];
    const float* ew = (const float*)d_in[1];
    const float* Wz = (const float*)d_in[2];
    const float* bz = (const float*)d_in[3];
    // d_in[4], d_in[5] = W_r, b_r: dead (H=0 => H*R=0 => R never used)
    const float* Wh = (const float*)d_in[6];
    const float* bh = (const float*)d_in[7];
    const float* Wl = (const float*)d_in[8];
    const float* bl = (const float*)d_in[9];
    const int* ei  = (const int*)d_in[10];
    const int* src = ei;
    const int* dst = ei + NE;

    // ws words: cnt/cur[TOT] | X[TOT+1] | bsum[256] | pad | adj[2E] int2 | gsum
    int* iws = (int*)d_ws;
    int* cnt  = iws;                        // doubles as scatter cursor after scan
    int* X    = iws + TOT;                  // TOT+1 entries
    int* bsum = iws + 2 * TOT + 1;          // 256 entries
    int adj_off = 2 * TOT + 1 + 256;
    adj_off = (adj_off + 1) & ~1;           // 8B-align for int2
    int2* adj = (int2*)(iws + adj_off);     // 2*NE entries
    float* gsum = (float*)(iws + adj_off + 4 * NE);

    init_kernel<<<(TOT + 255) / 256, 256, 0, stream>>>(cnt, gsum);
    count_kernel<<<(NE + 255) / 256, 256, 0, stream>>>(src, dst, cnt);
    scan1_kernel<<<SCAN_G, SCAN_B, 0, stream>>>(cnt, X, bsum);
    scan2_kernel<<<1, 256, 0, stream>>>(bsum);
    scan3_kernel<<<SCAN_G, SCAN_B, 0, stream>>>(X, bsum, cnt);
    scatter_kernel<<<(NE + 255) / 256, 256, 0, stream>>>(src, dst, ew, cnt, adj);
    RecurrentGCN_69587060130083_kernel<<<(NN * 4 + 255) / 256, 256, 0, stream>>>(
        x, X, adj, Wz, bz, Wh, bh, Wl, gsum);
    finalize_kernel<<<1, 1, 0, stream>>>(gsum, bl, (float*)d_out);
}

// Round 2
// 474.494 us; speedup vs baseline: 1.2384x; 1.2384x over previous
//
#include <hip/hip_runtime.h>

#define NN 100000
#define NE 1600000
#define F  32
#define TOT (2*NN)                 // concatenated out|in degree arrays
#define SCAN_B 1024
#define SCAN_G ((TOT + SCAN_B - 1) / SCAN_B)   // 196

#define XCDS 8
#define PART ((NN + XCDS - 1) / XCDS)          // 12500 nodes per XCD partition
#define EPB 1024                               // edges per block slice
#define GSLICES ((NE + EPB - 1) / EPB)         // 1563 slices; grid = 8*GSLICES

// ---- init: zero counters + gsum ----
__global__ void init_kernel(int* __restrict__ cnt, float* __restrict__ gsum) {
    int i = blockIdx.x * blockDim.x + threadIdx.x;
    if (i < TOT) cnt[i] = 0;
    if (i == 0) gsum[0] = 0.f;
}

// ---- XCD-partitioned degree count ----
// group g = blockIdx & 7 (round-robin blockIdx->XCD on MI355X): only counts nodes in
// partition g, so each counter line is touched by ONE XCD's L2 only.
__global__ __launch_bounds__(256) void count_kernel(const int* __restrict__ src,
                                                    const int* __restrict__ dst,
                                                    int* __restrict__ cnt) {
    int g = blockIdx.x & 7;
    int sub = blockIdx.x >> 3;
    int base = sub * EPB + threadIdx.x;
#pragma unroll
    for (int j = 0; j < EPB / 256; ++j) {
        int e = base + j * 256;
        if (e < NE) {
            int s = src[e];
            if (s / PART == g) atomicAdd(&cnt[s], 1);
            int d = dst[e];
            if (d / PART == g) atomicAdd(&cnt[NN + d], 1);
        }
    }
}

// ---- hierarchical exclusive scan over cnt[TOT] -> X[TOT] (+ sentinel later) ----
__global__ __launch_bounds__(1024) void scan1_kernel(const int* __restrict__ cnt,
                                                     int* __restrict__ X,
                                                     int* __restrict__ bsum) {
    __shared__ int s[SCAN_B];
    int t = threadIdx.x;
    int g = blockIdx.x * SCAN_B + t;
    int v = (g < TOT) ? cnt[g] : 0;
    s[t] = v;
    __syncthreads();
    for (int off = 1; off < SCAN_B; off <<= 1) {
        int a = (t >= off) ? s[t - off] : 0;
        __syncthreads();
        s[t] += a;
        __syncthreads();
    }
    if (g < TOT) X[g] = s[t] - v;          // block-local exclusive
    if (t == SCAN_B - 1) bsum[blockIdx.x] = s[t];
}

__global__ __launch_bounds__(256) void scan2_kernel(int* __restrict__ bsum) {
    __shared__ int s[256];
    int t = threadIdx.x;
    int v = (t < SCAN_G) ? bsum[t] : 0;
    s[t] = v;
    __syncthreads();
    for (int off = 1; off < 256; off <<= 1) {
        int a = (t >= off) ? s[t - off] : 0;
        __syncthreads();
        s[t] += a;
        __syncthreads();
    }
    if (t < SCAN_G) bsum[t] = s[t] - v;    // exclusive block offsets
}

// finalize offsets, write sentinel, and init scatter cursors (cur = cnt reused)
__global__ __launch_bounds__(1024) void scan3_kernel(int* __restrict__ X,
                                                     const int* __restrict__ bsum,
                                                     int* __restrict__ cur) {
    int g = blockIdx.x * SCAN_B + threadIdx.x;
    if (g < TOT) {
        int v = X[g] + bsum[blockIdx.x];
        X[g] = v;
        cur[g] = v;
    }
    if (g == 0) X[TOT] = 2 * NE;           // sentinel: end of in-part for node NN-1
}

// ---- XCD-partitioned CSR fill: adj[j] = {neighbor, weight_bits} ----
// Each group g writes ONLY the CSR regions of partition-g nodes -> those adj lines
// live in a single XCD's L2 (3.2 MB < 4 MB), accumulate fully, write back once.
__global__ __launch_bounds__(256) void scatter_kernel(const int* __restrict__ src,
                                                      const int* __restrict__ dst,
                                                      const float* __restrict__ ew,
                                                      int* __restrict__ cur,
                                                      int2* __restrict__ adj) {
    int g = blockIdx.x & 7;
    int sub = blockIdx.x >> 3;
    int base = sub * EPB + threadIdx.x;
#pragma unroll
    for (int j = 0; j < EPB / 256; ++j) {
        int e = base + j * 256;
        if (e < NE) {
            int s = src[e];
            int d = dst[e];
            bool ms = (s / PART == g);
            bool md = (d / PART == g);
            if (ms | md) {
                int wb = __float_as_int(ew[e]);
                if (ms) {
                    int p = atomicAdd(&cur[s], 1);
                    adj[p] = make_int2(d, wb);
                }
                if (md) {
                    int q = atomicAdd(&cur[NN + d], 1);
                    adj[q] = make_int2(s, wb);
                }
            }
        }
    }
}

// ---- fused gather + gates + reduction. 4 lanes per node, 8 features per lane. ----
// H = 0 initially => only the first 32 rows (c<32) of each 64x32 W slice matter,
// R-gate is dead, H_new = (1-sigmoid(gz)) * tanh(gh).
__global__ __launch_bounds__(256) void RecurrentGCN_69587060130083_kernel(
    const float* __restrict__ x,
    const int* __restrict__ X,          // CSR offsets [2*NN+1]
    const int2* __restrict__ adj,       // [2*NE]
    const float* __restrict__ Wz, const float* __restrict__ bz,
    const float* __restrict__ Wh, const float* __restrict__ bh,
    const float* __restrict__ Wl,
    float* __restrict__ gsum)
{
    // transposed [f][c] so per-f dot reads contiguous 8-float slices
    __shared__ float sWz0[1024], sWzo[1024], sWzi[1024];
    __shared__ float sWh0[1024], sWho[1024], sWhi[1024];
    __shared__ float sbz[32], sbh[32], swl[32];
    __shared__ float wsum[4];
    int tid = threadIdx.x;

    for (int idx = tid; idx < 1024; idx += 256) {
        int c = idx >> 5, f = idx & 31;
        int tr = f * 32 + c;
        // W[dir,k,c,f] flat = dir*4096 + k*2048 + c*32 + f ; only c<32 matters (H=0)
        sWz0[tr] = Wz[idx] + Wz[4096 + idx];
        sWzo[tr] = Wz[2048 + idx];
        sWzi[tr] = Wz[6144 + idx];
        sWh0[tr] = Wh[idx] + Wh[4096 + idx];
        sWho[tr] = Wh[2048 + idx];
        sWhi[tr] = Wh[6144 + idx];
    }
    if (tid < 32) {
        sbz[tid] = bz[tid];
        sbh[tid] = bh[tid];
        swl[tid] = Wl[tid];
    }
    __syncthreads();

    int q = tid & 3;                       // quartet lane: features [q*8, q*8+8)
    int i = (blockIdx.x * 256 + tid) >> 2; // node index (64 nodes per block)
    float s_acc = 0.f;

    if (i < NN) {
        const int cbase = q * 8;
        float xv[8], tov[8], tiv[8];
#pragma unroll
        for (int c = 0; c < 8; c++) { tov[c] = 0.f; tiv[c] = 0.f; }

        const float4* xr = (const float4*)(x + ((size_t)i << 5) + cbase);
        float4 p0 = xr[0], p1 = xr[1];
        xv[0] = p0.x; xv[1] = p0.y; xv[2] = p0.z; xv[3] = p0.w;
        xv[4] = p1.x; xv[5] = p1.y; xv[6] = p1.z; xv[7] = p1.w;

        // out-direction gather: contiguous CSR range, loads pipeline freely
        int r0 = X[i], r1 = X[i + 1];
        float deg_o = 0.f;
        for (int j = r0; j < r1; ++j) {
            int2 a = adj[j];
            float w = __int_as_float(a.y);
            deg_o += w;
            const float4* nr = (const float4*)(x + ((size_t)a.x << 5) + cbase);
            float4 b0 = nr[0], b1 = nr[1];
            tov[0] += w * b0.x; tov[1] += w * b0.y; tov[2] += w * b0.z; tov[3] += w * b0.w;
            tov[4] += w * b1.x; tov[5] += w * b1.y; tov[6] += w * b1.z; tov[7] += w * b1.w;
        }
        // in-direction gather
        int r2 = X[NN + i], r3 = X[NN + i + 1];
        float deg_i = 0.f;
        for (int j = r2; j < r3; ++j) {
            int2 a = adj[j];
            float w = __int_as_float(a.y);
            deg_i += w;
            const float4* nr = (const float4*)(x + ((size_t)a.x << 5) + cbase);
            float4 b0 = nr[0], b1 = nr[1];
            tiv[0] += w * b0.x; tiv[1] += w * b0.y; tiv[2] += w * b0.z; tiv[3] += w * b0.w;
            tiv[4] += w * b1.x; tiv[5] += w * b1.y; tiv[6] += w * b1.z; tiv[7] += w * b1.w;
        }
        float dio = 1.f / deg_o, dii = 1.f / deg_i;
#pragma unroll
        for (int c = 0; c < 8; c++) { tov[c] *= dio; tiv[c] *= dii; }

        // gates: per-f partial dot over this lane's 8 channels, quartet shuffle-reduce
#pragma unroll 4
        for (int f = 0; f < 32; ++f) {
            const float* wz0 = &sWz0[f * 32 + cbase];
            const float* wzo = &sWzo[f * 32 + cbase];
            const float* wzi = &sWzi[f * 32 + cbase];
            const float* wh0 = &sWh0[f * 32 + cbase];
            const float* who = &sWho[f * 32 + cbase];
            const float* whi = &sWhi[f * 32 + cbase];
            float pz = 0.f, ph = 0.f;
#pragma unroll
            for (int c = 0; c < 8; c++) {
                pz += xv[c] * wz0[c] + tov[c] * wzo[c] + tiv[c] * wzi[c];
                ph += xv[c] * wh0[c] + tov[c] * who[c] + tiv[c] * whi[c];
            }
            pz += __shfl_xor(pz, 1); pz += __shfl_xor(pz, 2);
            ph += __shfl_xor(ph, 1); ph += __shfl_xor(ph, 2);
            if (q == (f & 3)) {
                float gz = pz + sbz[f];
                float gh = ph + sbh[f];
                float Z  = 1.f / (1.f + __expf(-gz));
                float Ht = tanhf(gh);
                float hv = (1.f - Z) * Ht;
                hv = hv > 0.f ? hv : 0.f;
                s_acc += hv * swl[f];
            }
        }
    }

    // wave64 reduce -> cross-wave via LDS -> one atomic per block
#pragma unroll
    for (int off = 32; off > 0; off >>= 1) s_acc += __shfl_down(s_acc, off);
    if ((tid & 63) == 0) wsum[tid >> 6] = s_acc;
    __syncthreads();
    if (tid == 0) atomicAdd(gsum, wsum[0] + wsum[1] + wsum[2] + wsum[3]);
}

__global__ void finalize_kernel(const float* __restrict__ gsum,
                                const float* __restrict__ blin,
                                float* __restrict__ out) {
    out[0] = gsum[0] / (float)NN + blin[0];
}

extern "C" void kernel_launch(void* const* d_in, const int* in_sizes, int n_in,
                              void* d_out, int out_size, void* d_ws, size_t ws_size,
                              hipStream_t stream) {
    const float* x  = (const float*)d_in[0];
    const float* ew = (const float*)d_in[1];
    const float* Wz = (const float*)d_in[2];
    const float* bz = (const float*)d_in[3];
    // d_in[4], d_in[5] = W_r, b_r: dead (H=0 => H*R=0 => R never used)
    const float* Wh = (const float*)d_in[6];
    const float* bh = (const float*)d_in[7];
    const float* Wl = (const float*)d_in[8];
    const float* bl = (const float*)d_in[9];
    const int* ei  = (const int*)d_in[10];
    const int* src = ei;
    const int* dst = ei + NE;

    // ws words: cnt/cur[TOT] | X[TOT+1] | bsum[256] | pad | adj[2E] int2 | gsum
    int* iws = (int*)d_ws;
    int* cnt  = iws;                        // doubles as scatter cursor after scan
    int* X    = iws + TOT;                  // TOT+1 entries
    int* bsum = iws + 2 * TOT + 1;          // 256 entries
    int adj_off = 2 * TOT + 1 + 256;
    adj_off = (adj_off + 1) & ~1;           // 8B-align for int2
    int2* adj = (int2*)(iws + adj_off);     // 2*NE entries
    float* gsum = (float*)(iws + adj_off + 4 * NE);

    init_kernel<<<(TOT + 255) / 256, 256, 0, stream>>>(cnt, gsum);
    count_kernel<<<GSLICES * 8, 256, 0, stream>>>(src, dst, cnt);
    scan1_kernel<<<SCAN_G, SCAN_B, 0, stream>>>(cnt, X, bsum);
    scan2_kernel<<<1, 256, 0, stream>>>(bsum);
    scan3_kernel<<<SCAN_G, SCAN_B, 0, stream>>>(X, bsum, cnt);
    scatter_kernel<<<GSLICES * 8, 256, 0, stream>>>(src, dst, ew, cnt, adj);
    RecurrentGCN_69587060130083_kernel<<<(NN * 4 + 255) / 256, 256, 0, stream>>>(
        x, X, adj, Wz, bz, Wh, bh, Wl, gsum);
    finalize_kernel<<<1, 1, 0, stream>>>(gsum, bl, (float*)d_out);
}